// Round 14
// baseline (18956.581 us; speedup 1.0000x reference)
//
#include <hip/hip_runtime.h>
#include <cmath>

#define LL 6
#define NTOT 4194304
#define R0Q 3145727ULL   // 0-indexed rank: 0.75*(NTOT-1)=3145727.25 -> i=3145727, gamma=0.25

// ---------------------------------------------------------------------------
// numpy pairwise summation for n=512 (C3 SIMD variant, verified bit-exact R9).
__device__ __forceinline__ float pairwise512(const float* a, int lane) {
    float B0, B1, B2, B3;
    #pragma unroll
    for (int b = 0; b < 4; b++) {
        float s = 0.0f;
        if (lane < 32) {
            const float* p = a + b * 128 + lane;
            s = __fadd_rn(__fadd_rn(__fadd_rn(p[0], p[32]), p[64]), p[96]);
        }
        s = __fadd_rn(s, __shfl_xor(s, 4, 64));
        s = __fadd_rn(s, __shfl_xor(s, 8, 64));
        s = __fadd_rn(s, __shfl_xor(s, 16, 64));
        s = __fadd_rn(s, __shfl_xor(s, 1, 64));
        s = __fadd_rn(s, __shfl_xor(s, 2, 64));
        float bs = __shfl(s, 0, 64);
        if (b == 0) B0 = bs; else if (b == 1) B1 = bs; else if (b == 2) B2 = bs; else B3 = bs;
    }
    return __fadd_rn(__fadd_rn(B0, B1), __fadd_rn(B2, B3));
}

// numpy f32 SIMD exp (FMA path, Cephes constants) — verified bit-exact R9.
__device__ __forceinline__ float np_expf(float x) {
    float q = rintf(__fmul_rn(x, 1.44269504088896341f));
    float r = __builtin_fmaf(q, -0.693359375f, x);
    r = __builtin_fmaf(q, 2.12194440e-4f, r);
    float p = 1.9875691500e-4f;
    p = __builtin_fmaf(p, r, 1.3981999507e-3f);
    p = __builtin_fmaf(p, r, 8.3334519073e-3f);
    p = __builtin_fmaf(p, r, 4.1665795894e-2f);
    p = __builtin_fmaf(p, r, 1.6666665459e-1f);
    p = __builtin_fmaf(p, r, 5.0000001201e-1f);
    float r2 = __fmul_rn(r, r);
    p = __builtin_fmaf(p, r2, r);
    p = __fadd_rn(p, 1.0f);
    int qi = (int)q;
    float sc;
    if (qi >= -126) sc = __uint_as_float((unsigned)((qi + 127) << 23));
    else { sc = __uint_as_float((unsigned)((qi + 127 + 64) << 23));
           sc = __fmul_rn(sc, __uint_as_float((unsigned)((127 - 64) << 23))); }
    return __fmul_rn(p, sc);
}

// ---------------- embedding (unchanged) ----------------
__global__ __launch_bounds__(256) void k_embed32(const int* __restrict__ src,
                                                 const float* __restrict__ emb,
                                                 const float* __restrict__ pos,
                                                 float* __restrict__ x, float sc) {
    int idx = blockIdx.x * 256 + threadIdx.x;
    int row = idx >> 9, d = idx & 511, s = row & 511;
    int tok = src[row];
    x[idx] = __fadd_rn(__fmul_rn(emb[(size_t)tok * 512 + d], sc), pos[(size_t)s * 512 + d]);
}

// ---------------- f32 GEMM v6: 128x192 tile, 8x12/thread, 1-buf 2-barrier ---
// Per-element arithmetic identical to R9-R13: sequential-k FMA chain ascending,
// OpenBLAS K-block folds (K=512: @256; K=2048: @384,768,1152,1536,1792)
// realized as left-assoc global-C accumulation (bit-exact per R11).
// LDS byte-balance: 12(TM+TN)=240 vs 2*TM*TN=192 -> VALU cap ~80%
// (R13's 8x4: 288 vs 192 -> cap 44%, measured 35%). 4x4-block transposed
// staging: b128 global loads AND b128 LDS writes (no scalar-write tax).
__global__ __launch_bounds__(256) void k_gemm6(const float* __restrict__ A,
                                               const float* __restrict__ W,
                                               const float* __restrict__ bias,
                                               float* __restrict__ C,
                                               int N, int K, int flags) { // 1=bias, 2=relu
    __shared__ float As[16][128];
    __shared__ float Ws[16][192];
    int t = threadIdx.x;
    int tm = t & 15, tn = t >> 4;
    int row0 = blockIdx.y * 128, col0 = blockIdx.x * 192;
    // staging roles
    int r4 = t & 31, kca = (t >> 5) & 3;          // A: threads 0..127
    int wt = t - 64;                              // W: threads 64..255 (192 tasks)
    int c4 = 0, kcw = 0;
    if (t >= 64) { c4 = wt % 48; kcw = wt / 48; }
    float acc[8][12];
    #pragma unroll
    for (int i = 0; i < 8; i++)
        #pragma unroll
        for (int j = 0; j < 12; j++) acc[i][j] = 0.0f;
    int nt = K >> 4;
    bool wroteC = false;
    // ---- stage tile 0 ----
    {
        if (t < 128) {
            float4 av[4];
            #pragma unroll
            for (int i = 0; i < 4; i++)
                av[i] = *(const float4*)(A + (size_t)(row0 + 4 * r4 + i) * K + kca * 4);
            #pragma unroll
            for (int j = 0; j < 4; j++) {
                float4 v = make_float4(((float*)&av[0])[j], ((float*)&av[1])[j],
                                       ((float*)&av[2])[j], ((float*)&av[3])[j]);
                *(float4*)&As[kca * 4 + j][4 * r4] = v;
            }
        }
        if (t >= 64) {
            float4 wv[4];
            #pragma unroll
            for (int i = 0; i < 4; i++) {
                int col = col0 + 4 * c4 + i;
                wv[i] = (col < N) ? *(const float4*)(W + (size_t)col * K + kcw * 4)
                                  : make_float4(0.f, 0.f, 0.f, 0.f);
            }
            #pragma unroll
            for (int j = 0; j < 4; j++) {
                float4 v = make_float4(((float*)&wv[0])[j], ((float*)&wv[1])[j],
                                       ((float*)&wv[2])[j], ((float*)&wv[3])[j]);
                *(float4*)&Ws[kcw * 4 + j][4 * c4] = v;
            }
        }
    }
    __syncthreads();
    for (int tt = 0; tt < nt; tt++) {
        #pragma unroll
        for (int kk = 0; kk < 16; kk++) {
            float4 alo = *(const float4*)&As[kk][tm * 4];
            float4 ahi = *(const float4*)&As[kk][64 + tm * 4];
            float4 w0 = *(const float4*)&Ws[kk][tn * 12];
            float4 w1 = *(const float4*)&Ws[kk][tn * 12 + 4];
            float4 w2 = *(const float4*)&Ws[kk][tn * 12 + 8];
            float a[8] = {alo.x, alo.y, alo.z, alo.w, ahi.x, ahi.y, ahi.z, ahi.w};
            float w[12] = {w0.x, w0.y, w0.z, w0.w, w1.x, w1.y, w1.z, w1.w,
                           w2.x, w2.y, w2.z, w2.w};
            #pragma unroll
            for (int i = 0; i < 8; i++)
                #pragma unroll
                for (int j = 0; j < 12; j++)
                    acc[i][j] = __builtin_fmaf(a[i], w[j], acc[i][j]);
        }
        // OpenBLAS fold via C-roundtrip (left-assoc; verified R11)
        int ke = (tt + 1) << 4;
        bool fold = (K == 512) ? (ke == 256)
                  : ((ke <= 1536 && (ke % 384) == 0) || ke == 1792);
        if (fold && ke < K) {
            #pragma unroll
            for (int ih = 0; ih < 2; ih++)
                #pragma unroll
                for (int i = 0; i < 4; i++) {
                    int r = row0 + ih * 64 + tm * 4 + i;
                    int ai = ih * 4 + i;
                    #pragma unroll
                    for (int m = 0; m < 3; m++) {
                        int c = col0 + tn * 12 + m * 4;
                        if (c < N) {
                            float* Cp = &C[(size_t)r * N + c];
                            float v0 = acc[ai][m*4+0], v1 = acc[ai][m*4+1];
                            float v2 = acc[ai][m*4+2], v3 = acc[ai][m*4+3];
                            if (wroteC) {
                                float4 o = *(const float4*)Cp;
                                v0 = __fadd_rn(o.x, v0); v1 = __fadd_rn(o.y, v1);
                                v2 = __fadd_rn(o.z, v2); v3 = __fadd_rn(o.w, v3);
                            }
                            *(float4*)Cp = make_float4(v0, v1, v2, v3);
                        }
                    }
                }
            #pragma unroll
            for (int i = 0; i < 8; i++)
                #pragma unroll
                for (int j = 0; j < 12; j++) acc[i][j] = 0.0f;
            wroteC = true;
        }
        __syncthreads();   // all reads of this tile done
        if (tt + 1 < nt) {
            int k0 = (tt + 1) << 4;
            if (t < 128) {
                float4 av[4];
                #pragma unroll
                for (int i = 0; i < 4; i++)
                    av[i] = *(const float4*)(A + (size_t)(row0 + 4 * r4 + i) * K + k0 + kca * 4);
                #pragma unroll
                for (int j = 0; j < 4; j++) {
                    float4 v = make_float4(((float*)&av[0])[j], ((float*)&av[1])[j],
                                           ((float*)&av[2])[j], ((float*)&av[3])[j]);
                    *(float4*)&As[kca * 4 + j][4 * r4] = v;
                }
            }
            if (t >= 64) {
                float4 wv[4];
                #pragma unroll
                for (int i = 0; i < 4; i++) {
                    int col = col0 + 4 * c4 + i;
                    wv[i] = (col < N) ? *(const float4*)(W + (size_t)col * K + k0 + kcw * 4)
                                      : make_float4(0.f, 0.f, 0.f, 0.f);
                }
                #pragma unroll
                for (int j = 0; j < 4; j++) {
                    float4 v = make_float4(((float*)&wv[0])[j], ((float*)&wv[1])[j],
                                           ((float*)&wv[2])[j], ((float*)&wv[3])[j]);
                    *(float4*)&Ws[kcw * 4 + j][4 * c4] = v;
                }
            }
        }
        __syncthreads();   // next tile staged
    }
    // epilogue
    #pragma unroll
    for (int ih = 0; ih < 2; ih++)
        #pragma unroll
        for (int i = 0; i < 4; i++) {
            int r = row0 + ih * 64 + tm * 4 + i;
            int ai = ih * 4 + i;
            #pragma unroll
            for (int m = 0; m < 3; m++) {
                int c = col0 + tn * 12 + m * 4;
                if (c < N) {
                    float* Cp = &C[(size_t)r * N + c];
                    float v[4] = {acc[ai][m*4+0], acc[ai][m*4+1], acc[ai][m*4+2], acc[ai][m*4+3]};
                    if (wroteC) {
                        float4 o = *(const float4*)Cp;
                        v[0] = __fadd_rn(o.x, v[0]); v[1] = __fadd_rn(o.y, v[1]);
                        v[2] = __fadd_rn(o.z, v[2]); v[3] = __fadd_rn(o.w, v[3]);
                    }
                    if (flags & 1) {
                        #pragma unroll
                        for (int j = 0; j < 4; j++) v[j] = __fadd_rn(v[j], bias[c + j]);
                    }
                    if (flags & 2) {
                        #pragma unroll
                        for (int j = 0; j < 4; j++) v[j] = fmaxf(v[j], 0.0f);
                    }
                    *(float4*)Cp = make_float4(v[0], v[1], v[2], v[3]);
                }
            }
        }
}

// ---------------- attention scores (unchanged) ----------------
__global__ __launch_bounds__(256) void k_scores(const float* __restrict__ qkv,
                                                float* __restrict__ attnP, int b0) {
    __shared__ float Qs[64][64];
    __shared__ float Ks[64][64];
    int t = threadIdx.x;
    int bx = blockIdx.x;
    int kt = bx & 7, qt = (bx >> 3) & 7, h = (bx >> 6) & 7, bi = bx >> 9;
    int b = b0 + bi;
    {
        int r = t & 63, d0 = (t >> 6) * 16;
        const float* qp = qkv + (size_t)(b * 512 + qt * 64 + r) * 1536 + h * 64 + d0;
        const float* kp = qkv + (size_t)(b * 512 + kt * 64 + r) * 1536 + 512 + h * 64 + d0;
        #pragma unroll
        for (int m = 0; m < 4; m++) {
            float4 vq = *(const float4*)(qp + 4 * m);
            float4 vk = *(const float4*)(kp + 4 * m);
            Qs[d0 + 4 * m + 0][r] = vq.x; Qs[d0 + 4 * m + 1][r] = vq.y;
            Qs[d0 + 4 * m + 2][r] = vq.z; Qs[d0 + 4 * m + 3][r] = vq.w;
            Ks[d0 + 4 * m + 0][r] = vk.x; Ks[d0 + 4 * m + 1][r] = vk.y;
            Ks[d0 + 4 * m + 2][r] = vk.z; Ks[d0 + 4 * m + 3][r] = vk.w;
        }
    }
    __syncthreads();
    int tm = t & 15, tn = t >> 4;
    float acc[4][4][4];
    #pragma unroll
    for (int i = 0; i < 4; i++)
        #pragma unroll
        for (int j = 0; j < 4; j++)
            #pragma unroll
            for (int m = 0; m < 4; m++) acc[i][j][m] = 0.0f;
    #pragma unroll
    for (int d = 0; d < 64; d++) {
        float4 vq = *(const float4*)&Qs[d][tm * 4];
        float4 vk = *(const float4*)&Ks[d][tn * 4];
        float qa[4] = {vq.x, vq.y, vq.z, vq.w};
        float kb[4] = {vk.x, vk.y, vk.z, vk.w};
        const int m = d & 3;
        #pragma unroll
        for (int i = 0; i < 4; i++)
            #pragma unroll
            for (int j = 0; j < 4; j++)
                acc[i][j][m] = __fadd_rn(acc[i][j][m], __fmul_rn(qa[i], kb[j]));
    }
    size_t rb = ((size_t)(bi * 8 + h) * 512 + qt * 64);
    #pragma unroll
    for (int i = 0; i < 4; i++) {
        float4 o;
        o.x = __fmul_rn(__fadd_rn(__fadd_rn(acc[i][0][0], acc[i][0][1]), __fadd_rn(acc[i][0][2], acc[i][0][3])), 0.125f);
        o.y = __fmul_rn(__fadd_rn(__fadd_rn(acc[i][1][0], acc[i][1][1]), __fadd_rn(acc[i][1][2], acc[i][1][3])), 0.125f);
        o.z = __fmul_rn(__fadd_rn(__fadd_rn(acc[i][2][0], acc[i][2][1]), __fadd_rn(acc[i][2][2], acc[i][2][3])), 0.125f);
        o.w = __fmul_rn(__fadd_rn(__fadd_rn(acc[i][3][0], acc[i][3][1]), __fadd_rn(acc[i][3][2], acc[i][3][3])), 0.125f);
        *(float4*)&attnP[(rb + tm * 4 + i) * 512 + kt * 64 + tn * 4] = o;
    }
}

// ---------------- softmax (unchanged) ----------------
__global__ __launch_bounds__(256) void k_softmax(float* __restrict__ attnP) {
    __shared__ float ebuf[4][512];
    int wid = threadIdx.x >> 6, lane = threadIdx.x & 63;
    int row = blockIdx.x * 4 + wid;
    float* pr = attnP + (size_t)row * 512;
    float s[8], m = -INFINITY;
    for (int i = 0; i < 8; i++) { s[i] = pr[i * 64 + lane]; m = fmaxf(m, s[i]); }
    for (int off = 32; off; off >>= 1) m = fmaxf(m, __shfl_xor(m, off, 64));
    for (int i = 0; i < 8; i++)
        ebuf[wid][i * 64 + lane] = np_expf(__fsub_rn(s[i], m));
    __syncthreads();
    float sum = pairwise512(ebuf[wid], lane);
    for (int i = 0; i < 8; i++) pr[i * 64 + lane] = __fdiv_rn(ebuf[wid][i * 64 + lane], sum);
}

// ---------------- PV v2 (unchanged) ----------------
__global__ __launch_bounds__(256) void k_pv(const float* __restrict__ attnP,
                                            const float* __restrict__ qkv,
                                            float* __restrict__ ctx, int b0) {
    __shared__ float at_s[64][64];   // [k][q]
    __shared__ float v_s[64][64];    // [k][dh]
    int t = threadIdx.x;
    int bx = blockIdx.x;
    int qt = bx & 7, h = (bx >> 3) & 7, bi = bx >> 6;
    int b = b0 + bi;
    int tm = t & 15, tn = t >> 4;
    int lr = t >> 2, lf = (t & 3) * 16;
    float acc[4][4] = {};
    for (int c = 0; c < 8; c++) {
        const float* ar = attnP + ((size_t)(bi * 8 + h) * 512 + qt * 64 + lr) * 512 + c * 64 + lf;
        #pragma unroll
        for (int m = 0; m < 4; m++) {
            float4 a4 = *(const float4*)(ar + 4 * m);
            at_s[lf + 4 * m + 0][lr] = a4.x;
            at_s[lf + 4 * m + 1][lr] = a4.y;
            at_s[lf + 4 * m + 2][lr] = a4.z;
            at_s[lf + 4 * m + 3][lr] = a4.w;
        }
        const float* vr = qkv + (size_t)(b * 512 + c * 64 + lr) * 1536 + 1024 + h * 64 + lf;
        #pragma unroll
        for (int m = 0; m < 4; m++)
            *(float4*)&v_s[lr][lf + 4 * m] = *(const float4*)(vr + 4 * m);
        __syncthreads();
        #pragma unroll
        for (int kk = 0; kk < 64; kk++) {
            float4 a4 = *(const float4*)&at_s[kk][tm * 4];
            float4 v4 = *(const float4*)&v_s[kk][tn * 4];
            float av[4] = {a4.x, a4.y, a4.z, a4.w};
            float bv[4] = {v4.x, v4.y, v4.z, v4.w};
            #pragma unroll
            for (int i = 0; i < 4; i++)
                #pragma unroll
                for (int j = 0; j < 4; j++)
                    acc[i][j] = __fadd_rn(acc[i][j], __fmul_rn(av[i], bv[j]));
        }
        __syncthreads();
    }
    #pragma unroll
    for (int i = 0; i < 4; i++) {
        int q = qt * 64 + tm * 4 + i;
        *(float4*)&ctx[(size_t)(b * 512 + q) * 512 + h * 64 + tn * 4] =
            make_float4(acc[i][0], acc[i][1], acc[i][2], acc[i][3]);
    }
}

// ---------------- residual + LayerNorm (unchanged) ----------------
__global__ __launch_bounds__(256) void k_addln32(const float* __restrict__ xin,
                                                 const float* __restrict__ yin,
                                                 const float* __restrict__ ob,
                                                 const float* __restrict__ sc,
                                                 const float* __restrict__ bi,
                                                 float* __restrict__ xout) {
    __shared__ float buf[512];
    __shared__ float d2[512];
    __shared__ float stats[2];
    int row = blockIdx.x, t = threadIdx.x;
    const float* xr = xin + (size_t)row * 512;
    const float* yr = yin + (size_t)row * 512;
    float v0 = __fadd_rn(xr[t], yr[t]);
    float v1 = __fadd_rn(xr[t + 256], yr[t + 256]);
    if (ob) { v0 = __fadd_rn(v0, ob[t]); v1 = __fadd_rn(v1, ob[t + 256]); }
    buf[t] = v0; buf[t + 256] = v1;
    __syncthreads();
    int lane = t & 63;
    if (t < 64) {
        float s = pairwise512(buf, lane);
        if (lane == 0) stats[0] = __fdiv_rn(s, 512.0f);
    }
    __syncthreads();
    float mean = stats[0];
    float d0 = __fsub_rn(v0, mean), d1 = __fsub_rn(v1, mean);
    d2[t] = __fmul_rn(d0, d0); d2[t + 256] = __fmul_rn(d1, d1);
    __syncthreads();
    if (t < 64) {
        float s = pairwise512(d2, lane);
        if (lane == 0) {
            float var = __fdiv_rn(s, 512.0f);
            stats[1] = __fdiv_rn(1.0f, __fsqrt_rn(__fadd_rn(var, 1e-5f)));
        }
    }
    __syncthreads();
    float inv = stats[1];
    xout[(size_t)row * 512 + t]       = __fadd_rn(__fmul_rn(__fmul_rn(d0, inv), sc[t]), bi[t]);
    xout[(size_t)row * 512 + t + 256] = __fadd_rn(__fmul_rn(__fmul_rn(d1, inv), sc[t + 256]), bi[t + 256]);
}

// ---------------- sdot (unchanged: exact chains — DO NOT TOUCH) -------------
__global__ __launch_bounds__(256) void k_sdot(const float* __restrict__ x,
                                              float* __restrict__ den) {
    __shared__ float sbuf[2][4096];
    int t = threadIdx.x;
    #pragma unroll
    for (int q = 0; q < 4; q++)
        *(float4*)&sbuf[0][q * 1024 + t * 4] = *(const float4*)&x[q * 1024 + t * 4];
    __syncthreads();
    float acc = 0.0f;
    for (int ch = 0; ch < 1024; ch++) {
        int p = ch & 1;
        if (ch + 1 < 1024) {
            const float* src = x + (size_t)(ch + 1) * 4096;
            #pragma unroll
            for (int q = 0; q < 4; q++)
                *(float4*)&sbuf[p ^ 1][q * 1024 + t * 4] = *(const float4*)&src[q * 1024 + t * 4];
        }
        if (t < 32) {
            const float* bp = sbuf[p];
            #pragma unroll 16
            for (int jj = 0; jj < 128; jj++) {
                float v = bp[jj * 32 + t];
                acc = __builtin_fmaf(v, v, acc);
            }
        }
        __syncthreads();
    }
    acc = __fadd_rn(acc, __shfl_xor(acc, 8, 64));
    acc = __fadd_rn(acc, __shfl_xor(acc, 16, 64));
    acc = __fadd_rn(acc, __shfl_xor(acc, 4, 64));
    acc = __fadd_rn(acc, __shfl_xor(acc, 1, 64));
    acc = __fadd_rn(acc, __shfl_xor(acc, 2, 64));
    if (t == 0) den[0] = __fadd_rn(__fsqrt_rn(acc), 1e-8f);
}

// ---------------- quantile machinery (unchanged) ----------------
__global__ void k_qinit(unsigned long long* state, unsigned int* hist) {
    int t = threadIdx.x;
    hist[t] = 0;
    if (t == 0) { state[0] = 0; state[1] = R0Q; state[2] = 0; state[3] = ~0ULL; }
}

__global__ __launch_bounds__(256) void k_gkeys32(const float* __restrict__ x,
                                                 const float* __restrict__ den_p,
                                                 unsigned int* __restrict__ keys) {
    int i = blockIdx.x * 256 + threadIdx.x;
    float g = __fmul_rn(__fdiv_rn(x[i], den_p[0]), 2048.0f);
    keys[i] = __float_as_uint(fabsf(g));
}

__global__ __launch_bounds__(256) void k_hist32(const unsigned int* __restrict__ keys,
                                                const unsigned long long* __restrict__ state,
                                                unsigned int* __restrict__ hist, int shift) {
    __shared__ unsigned int h[256];
    h[threadIdx.x] = 0;
    __syncthreads();
    unsigned int pref = (unsigned int)state[0];
    for (size_t i = (size_t)blockIdx.x * 256 + threadIdx.x; i < (size_t)NTOT; i += 262144) {
        unsigned int k = keys[i];
        if (shift == 24 || (k >> (shift + 8)) == pref)
            atomicAdd(&h[(k >> shift) & 255u], 1u);
    }
    __syncthreads();
    atomicAdd(&hist[threadIdx.x], h[threadIdx.x]);
}

__global__ void k_scan32(unsigned long long* state, unsigned int* hist) {
    if (threadIdx.x == 0) {
        unsigned long long r = state[1], cum = 0;
        int b = 0;
        for (; b < 256; b++) {
            unsigned long long c = hist[b];
            if (cum + c > r) break;
            cum += c;
        }
        state[0] = (state[0] << 8) | (unsigned long long)b;
        state[1] = r - cum;
    }
    __syncthreads();
    hist[threadIdx.x] = 0;
}

__global__ __launch_bounds__(256) void k_fixcnt32(const unsigned int* __restrict__ keys,
                                                  unsigned long long* __restrict__ state) {
    __shared__ unsigned long long lc[4];
    __shared__ unsigned int lm[4];
    unsigned int v0 = (unsigned int)state[0];
    unsigned long long cnt = 0;
    unsigned int mn = 0xFFFFFFFFu;
    for (size_t i = (size_t)blockIdx.x * 256 + threadIdx.x; i < (size_t)NTOT; i += 262144) {
        unsigned int k = keys[i];
        if (k <= v0) cnt++;
        else if (k < mn) mn = k;
    }
    for (int off = 32; off; off >>= 1) {
        cnt += __shfl_xor(cnt, off, 64);
        unsigned int o = __shfl_xor(mn, off, 64);
        if (o < mn) mn = o;
    }
    int wid = threadIdx.x >> 6, ln = threadIdx.x & 63;
    if (ln == 0) { lc[wid] = cnt; lm[wid] = mn; }
    __syncthreads();
    if (threadIdx.x == 0) {
        unsigned long long c = lc[0] + lc[1] + lc[2] + lc[3];
        unsigned int m2 = lm[0];
        if (lm[1] < m2) m2 = lm[1];
        if (lm[2] < m2) m2 = lm[2];
        if (lm[3] < m2) m2 = lm[3];
        atomicAdd(&state[2], c);
        atomicMin(&state[3], (unsigned long long)m2);
    }
}

__global__ void k_thr32(const unsigned long long* __restrict__ state,
                        float* __restrict__ thr_p) {
    if (threadIdx.x == 0 && blockIdx.x == 0) {
        float a = __uint_as_float((unsigned int)state[0]);
        float b = (state[2] > R0Q + 1) ? a : __uint_as_float((unsigned int)state[3]);
        thr_p[0] = __fadd_rn(a, __fmul_rn(__fsub_rn(b, a), 0.25f));
    }
}

__global__ __launch_bounds__(256) void k_damp32(float* __restrict__ x,
                                                const float* __restrict__ den_p,
                                                const float* __restrict__ thr_p,
                                                float c1, float c2) {
    int i = blockIdx.x * 256 + threadIdx.x;
    float g = __fmul_rn(__fdiv_rn(x[i], den_p[0]), 2048.0f);
    float v = (fabsf(g) > thr_p[0]) ? g : 0.0f;
    x[i] = __fmul_rn(__fmul_rn(v, c1), c2);
}

// ---------------- host orchestration ----------------------------------------
extern "C" void kernel_launch(void* const* d_in, const int* in_sizes, int n_in,
                              void* d_out, int out_size, void* d_ws, size_t ws_size,
                              hipStream_t stream) {
    const int*   src     = (const int*)d_in[0];
    const float* emb     = (const float*)d_in[1];
    const float* pos     = (const float*)d_in[2];
    const float* qkv_w   = (const float*)d_in[3];
    const float* qkv_b   = (const float*)d_in[4];
    const float* attn_ow = (const float*)d_in[5];
    const float* attn_ob = (const float*)d_in[6];
    const float* ln1_s   = (const float*)d_in[7];
    const float* ln1_b   = (const float*)d_in[8];
    const float* ln2_s   = (const float*)d_in[9];
    const float* ln2_b   = (const float*)d_in[10];
    const float* ff1_w   = (const float*)d_in[11];
    const float* ff1_b   = (const float*)d_in[12];
    const float* ff2_w   = (const float*)d_in[13];
    const float* ff2_b   = (const float*)d_in[14];
    const float* head_w  = (const float*)d_in[15];
    const float* head_b  = (const float*)d_in[16];

    char* ws = (char*)d_ws;
    float* x    = (float*)(ws + 0);
    float* qkv  = (float*)(ws + 16777216ULL);           // 50.3 MB
    float* attnP= (float*)(ws + 67108864ULL);           // 67.1 MB (8 batches) — aliases ffh
    float* ffh  = (float*)(ws + 67108864ULL);           // ff hidden (after attention)
    float* y    = (float*)(ws + 134217728ULL);
    float* ctx  = (float*)(ws + 150994944ULL);
    unsigned int* keys = (unsigned int*)ctx;            // aliases ctx (dead by then)
    float*  den  = (float*)(ws + 184557568ULL);
    float*  thr  = (float*)(ws + 184557572ULL);
    unsigned int* hist = (unsigned int*)(ws + 184561664ULL);
    unsigned long long* state = (unsigned long long*)(ws + 184565760ULL);

    float sc_emb = (float)sqrt(512.0);                 // np.sqrt(D).astype(f32)
    float c1 = (float)pow(0.99, 1.0 / 6.0);            // np.float32(DAMP**(1/L))

    k_embed32<<<16384, 256, 0, stream>>>(src, emb, pos, x, sc_emb);

    for (int l = 0; l < LL; l++) {
        // qkv = x @ qkv_w^T + qkv_b   [8192,1536]
        k_gemm6<<<dim3(8, 64), 256, 0, stream>>>(
            x, qkv_w + (size_t)l * 1536 * 512, qkv_b + (size_t)l * 1536, qkv, 1536, 512, 1);
        // attention: 2 phases of 8 batches
        for (int ph = 0; ph < 2; ph++) {
            int b0 = ph * 8;
            k_scores<<<4096, 256, 0, stream>>>(qkv, attnP, b0);
            k_softmax<<<8192, 256, 0, stream>>>(attnP);
            k_pv<<<512, 256, 0, stream>>>(attnP, qkv, ctx, b0);
        }
        // proj (raw matmul; ob added in addln to match ((x + mm) + ob) order)
        k_gemm6<<<dim3(3, 64), 256, 0, stream>>>(
            ctx, attn_ow + (size_t)l * 512 * 512, nullptr, y, 512, 512, 0);
        k_addln32<<<8192, 256, 0, stream>>>(x, y, attn_ob + (size_t)l * 512,
                                            ln1_s + (size_t)l * 512, ln1_b + (size_t)l * 512, x);
        // FF
        k_gemm6<<<dim3(11, 64), 256, 0, stream>>>(
            x, ff1_w + (size_t)l * 2048 * 512, ff1_b + (size_t)l * 2048, ffh, 2048, 512, 3);
        k_gemm6<<<dim3(3, 64), 256, 0, stream>>>(
            ffh, ff2_w + (size_t)l * 512 * 2048, ff2_b + (size_t)l * 512, y, 512, 2048, 1);
        k_addln32<<<8192, 256, 0, stream>>>(x, y, nullptr,
                                            ln2_s + (size_t)l * 512, ln2_b + (size_t)l * 512, x);
        // resonance: exact sdot norm, radix-select quantile, threshold+damp
        k_sdot<<<1, 256, 0, stream>>>(x, den);
        k_qinit<<<1, 256, 0, stream>>>(state, hist);
        k_gkeys32<<<16384, 256, 0, stream>>>(x, den, keys);
        for (int p = 0; p < 4; p++) {
            k_hist32<<<1024, 256, 0, stream>>>(keys, state, hist, 24 - 8 * p);
            k_scan32<<<1, 256, 0, stream>>>(state, hist);
        }
        k_fixcnt32<<<1024, 256, 0, stream>>>(keys, state);
        k_thr32<<<1, 1, 0, stream>>>(state, thr);
        float c2 = (float)pow(0.99, (double)l / 6.0);  // np.float32(DAMP**(i/L))
        k_damp32<<<16384, 256, 0, stream>>>(x, den, thr, c1, c2);
    }

    // head: out = x @ head_w^T + head_b   [8192,10000]
    k_gemm6<<<dim3(53, 64), 256, 0, stream>>>(
        x, head_w, head_b, (float*)d_out, 10000, 512, 1);
}

// Round 15
// 10599.788 us; speedup vs baseline: 1.7884x; 1.7884x over previous
//
#include <hip/hip_runtime.h>
#include <cmath>

#define LL 6
#define NTOT 4194304
#define R0Q 3145727ULL   // 0-indexed rank: 0.75*(NTOT-1)=3145727.25 -> i=3145727, gamma=0.25

// ---------------------------------------------------------------------------
// numpy pairwise summation for n=512 (C3 SIMD variant, verified bit-exact R9).
__device__ __forceinline__ float pairwise512(const float* a, int lane) {
    float B0, B1, B2, B3;
    #pragma unroll
    for (int b = 0; b < 4; b++) {
        float s = 0.0f;
        if (lane < 32) {
            const float* p = a + b * 128 + lane;
            s = __fadd_rn(__fadd_rn(__fadd_rn(p[0], p[32]), p[64]), p[96]);
        }
        s = __fadd_rn(s, __shfl_xor(s, 4, 64));
        s = __fadd_rn(s, __shfl_xor(s, 8, 64));
        s = __fadd_rn(s, __shfl_xor(s, 16, 64));
        s = __fadd_rn(s, __shfl_xor(s, 1, 64));
        s = __fadd_rn(s, __shfl_xor(s, 2, 64));
        float bs = __shfl(s, 0, 64);
        if (b == 0) B0 = bs; else if (b == 1) B1 = bs; else if (b == 2) B2 = bs; else B3 = bs;
    }
    return __fadd_rn(__fadd_rn(B0, B1), __fadd_rn(B2, B3));
}

// numpy f32 SIMD exp (FMA path, Cephes constants) — verified bit-exact R9.
__device__ __forceinline__ float np_expf(float x) {
    float q = rintf(__fmul_rn(x, 1.44269504088896341f));
    float r = __builtin_fmaf(q, -0.693359375f, x);
    r = __builtin_fmaf(q, 2.12194440e-4f, r);
    float p = 1.9875691500e-4f;
    p = __builtin_fmaf(p, r, 1.3981999507e-3f);
    p = __builtin_fmaf(p, r, 8.3334519073e-3f);
    p = __builtin_fmaf(p, r, 4.1665795894e-2f);
    p = __builtin_fmaf(p, r, 1.6666665459e-1f);
    p = __builtin_fmaf(p, r, 5.0000001201e-1f);
    float r2 = __fmul_rn(r, r);
    p = __builtin_fmaf(p, r2, r);
    p = __fadd_rn(p, 1.0f);
    int qi = (int)q;
    float sc;
    if (qi >= -126) sc = __uint_as_float((unsigned)((qi + 127) << 23));
    else { sc = __uint_as_float((unsigned)((qi + 127 + 64) << 23));
           sc = __fmul_rn(sc, __uint_as_float((unsigned)((127 - 64) << 23))); }
    return __fmul_rn(p, sc);
}

// ---------------- embedding (unchanged) ----------------
__global__ __launch_bounds__(256) void k_embed32(const int* __restrict__ src,
                                                 const float* __restrict__ emb,
                                                 const float* __restrict__ pos,
                                                 float* __restrict__ x, float sc) {
    int idx = blockIdx.x * 256 + threadIdx.x;
    int row = idx >> 9, d = idx & 511, s = row & 511;
    int tok = src[row];
    x[idx] = __fadd_rn(__fmul_rn(emb[(size_t)tok * 512 + d], sc), pos[(size_t)s * 512 + d]);
}

// ---------------- f32 GEMM v6 (unchanged from R14) ----------------
__global__ __launch_bounds__(256) void k_gemm6(const float* __restrict__ A,
                                               const float* __restrict__ W,
                                               const float* __restrict__ bias,
                                               float* __restrict__ C,
                                               int N, int K, int flags) { // 1=bias, 2=relu
    __shared__ float As[16][128];
    __shared__ float Ws[16][192];
    int t = threadIdx.x;
    int tm = t & 15, tn = t >> 4;
    int row0 = blockIdx.y * 128, col0 = blockIdx.x * 192;
    int r4 = t & 31, kca = (t >> 5) & 3;
    int wt = t - 64;
    int c4 = 0, kcw = 0;
    if (t >= 64) { c4 = wt % 48; kcw = wt / 48; }
    float acc[8][12];
    #pragma unroll
    for (int i = 0; i < 8; i++)
        #pragma unroll
        for (int j = 0; j < 12; j++) acc[i][j] = 0.0f;
    int nt = K >> 4;
    bool wroteC = false;
    {
        if (t < 128) {
            float4 av[4];
            #pragma unroll
            for (int i = 0; i < 4; i++)
                av[i] = *(const float4*)(A + (size_t)(row0 + 4 * r4 + i) * K + kca * 4);
            #pragma unroll
            for (int j = 0; j < 4; j++) {
                float4 v = make_float4(((float*)&av[0])[j], ((float*)&av[1])[j],
                                       ((float*)&av[2])[j], ((float*)&av[3])[j]);
                *(float4*)&As[kca * 4 + j][4 * r4] = v;
            }
        }
        if (t >= 64) {
            float4 wv[4];
            #pragma unroll
            for (int i = 0; i < 4; i++) {
                int col = col0 + 4 * c4 + i;
                wv[i] = (col < N) ? *(const float4*)(W + (size_t)col * K + kcw * 4)
                                  : make_float4(0.f, 0.f, 0.f, 0.f);
            }
            #pragma unroll
            for (int j = 0; j < 4; j++) {
                float4 v = make_float4(((float*)&wv[0])[j], ((float*)&wv[1])[j],
                                       ((float*)&wv[2])[j], ((float*)&wv[3])[j]);
                *(float4*)&Ws[kcw * 4 + j][4 * c4] = v;
            }
        }
    }
    __syncthreads();
    for (int tt = 0; tt < nt; tt++) {
        #pragma unroll
        for (int kk = 0; kk < 16; kk++) {
            float4 alo = *(const float4*)&As[kk][tm * 4];
            float4 ahi = *(const float4*)&As[kk][64 + tm * 4];
            float4 w0 = *(const float4*)&Ws[kk][tn * 12];
            float4 w1 = *(const float4*)&Ws[kk][tn * 12 + 4];
            float4 w2 = *(const float4*)&Ws[kk][tn * 12 + 8];
            float a[8] = {alo.x, alo.y, alo.z, alo.w, ahi.x, ahi.y, ahi.z, ahi.w};
            float w[12] = {w0.x, w0.y, w0.z, w0.w, w1.x, w1.y, w1.z, w1.w,
                           w2.x, w2.y, w2.z, w2.w};
            #pragma unroll
            for (int i = 0; i < 8; i++)
                #pragma unroll
                for (int j = 0; j < 12; j++)
                    acc[i][j] = __builtin_fmaf(a[i], w[j], acc[i][j]);
        }
        int ke = (tt + 1) << 4;
        bool fold = (K == 512) ? (ke == 256)
                  : ((ke <= 1536 && (ke % 384) == 0) || ke == 1792);
        if (fold && ke < K) {
            #pragma unroll
            for (int ih = 0; ih < 2; ih++)
                #pragma unroll
                for (int i = 0; i < 4; i++) {
                    int r = row0 + ih * 64 + tm * 4 + i;
                    int ai = ih * 4 + i;
                    #pragma unroll
                    for (int m = 0; m < 3; m++) {
                        int c = col0 + tn * 12 + m * 4;
                        if (c < N) {
                            float* Cp = &C[(size_t)r * N + c];
                            float v0 = acc[ai][m*4+0], v1 = acc[ai][m*4+1];
                            float v2 = acc[ai][m*4+2], v3 = acc[ai][m*4+3];
                            if (wroteC) {
                                float4 o = *(const float4*)Cp;
                                v0 = __fadd_rn(o.x, v0); v1 = __fadd_rn(o.y, v1);
                                v2 = __fadd_rn(o.z, v2); v3 = __fadd_rn(o.w, v3);
                            }
                            *(float4*)Cp = make_float4(v0, v1, v2, v3);
                        }
                    }
                }
            #pragma unroll
            for (int i = 0; i < 8; i++)
                #pragma unroll
                for (int j = 0; j < 12; j++) acc[i][j] = 0.0f;
            wroteC = true;
        }
        __syncthreads();
        if (tt + 1 < nt) {
            int k0 = (tt + 1) << 4;
            if (t < 128) {
                float4 av[4];
                #pragma unroll
                for (int i = 0; i < 4; i++)
                    av[i] = *(const float4*)(A + (size_t)(row0 + 4 * r4 + i) * K + k0 + kca * 4);
                #pragma unroll
                for (int j = 0; j < 4; j++) {
                    float4 v = make_float4(((float*)&av[0])[j], ((float*)&av[1])[j],
                                           ((float*)&av[2])[j], ((float*)&av[3])[j]);
                    *(float4*)&As[kca * 4 + j][4 * r4] = v;
                }
            }
            if (t >= 64) {
                float4 wv[4];
                #pragma unroll
                for (int i = 0; i < 4; i++) {
                    int col = col0 + 4 * c4 + i;
                    wv[i] = (col < N) ? *(const float4*)(W + (size_t)col * K + k0 + kcw * 4)
                                      : make_float4(0.f, 0.f, 0.f, 0.f);
                }
                #pragma unroll
                for (int j = 0; j < 4; j++) {
                    float4 v = make_float4(((float*)&wv[0])[j], ((float*)&wv[1])[j],
                                           ((float*)&wv[2])[j], ((float*)&wv[3])[j]);
                    *(float4*)&Ws[kcw * 4 + j][4 * c4] = v;
                }
            }
        }
        __syncthreads();
    }
    #pragma unroll
    for (int ih = 0; ih < 2; ih++)
        #pragma unroll
        for (int i = 0; i < 4; i++) {
            int r = row0 + ih * 64 + tm * 4 + i;
            int ai = ih * 4 + i;
            #pragma unroll
            for (int m = 0; m < 3; m++) {
                int c = col0 + tn * 12 + m * 4;
                if (c < N) {
                    float* Cp = &C[(size_t)r * N + c];
                    float v[4] = {acc[ai][m*4+0], acc[ai][m*4+1], acc[ai][m*4+2], acc[ai][m*4+3]};
                    if (wroteC) {
                        float4 o = *(const float4*)Cp;
                        v[0] = __fadd_rn(o.x, v[0]); v[1] = __fadd_rn(o.y, v[1]);
                        v[2] = __fadd_rn(o.z, v[2]); v[3] = __fadd_rn(o.w, v[3]);
                    }
                    if (flags & 1) {
                        #pragma unroll
                        for (int j = 0; j < 4; j++) v[j] = __fadd_rn(v[j], bias[c + j]);
                    }
                    if (flags & 2) {
                        #pragma unroll
                        for (int j = 0; j < 4; j++) v[j] = fmaxf(v[j], 0.0f);
                    }
                    *(float4*)Cp = make_float4(v[0], v[1], v[2], v[3]);
                }
            }
        }
}

// ---------------- attention scores (unchanged) ----------------
__global__ __launch_bounds__(256) void k_scores(const float* __restrict__ qkv,
                                                float* __restrict__ attnP, int b0) {
    __shared__ float Qs[64][64];
    __shared__ float Ks[64][64];
    int t = threadIdx.x;
    int bx = blockIdx.x;
    int kt = bx & 7, qt = (bx >> 3) & 7, h = (bx >> 6) & 7, bi = bx >> 9;
    int b = b0 + bi;
    {
        int r = t & 63, d0 = (t >> 6) * 16;
        const float* qp = qkv + (size_t)(b * 512 + qt * 64 + r) * 1536 + h * 64 + d0;
        const float* kp = qkv + (size_t)(b * 512 + kt * 64 + r) * 1536 + 512 + h * 64 + d0;
        #pragma unroll
        for (int m = 0; m < 4; m++) {
            float4 vq = *(const float4*)(qp + 4 * m);
            float4 vk = *(const float4*)(kp + 4 * m);
            Qs[d0 + 4 * m + 0][r] = vq.x; Qs[d0 + 4 * m + 1][r] = vq.y;
            Qs[d0 + 4 * m + 2][r] = vq.z; Qs[d0 + 4 * m + 3][r] = vq.w;
            Ks[d0 + 4 * m + 0][r] = vk.x; Ks[d0 + 4 * m + 1][r] = vk.y;
            Ks[d0 + 4 * m + 2][r] = vk.z; Ks[d0 + 4 * m + 3][r] = vk.w;
        }
    }
    __syncthreads();
    int tm = t & 15, tn = t >> 4;
    float acc[4][4][4];
    #pragma unroll
    for (int i = 0; i < 4; i++)
        #pragma unroll
        for (int j = 0; j < 4; j++)
            #pragma unroll
            for (int m = 0; m < 4; m++) acc[i][j][m] = 0.0f;
    #pragma unroll
    for (int d = 0; d < 64; d++) {
        float4 vq = *(const float4*)&Qs[d][tm * 4];
        float4 vk = *(const float4*)&Ks[d][tn * 4];
        float qa[4] = {vq.x, vq.y, vq.z, vq.w};
        float kb[4] = {vk.x, vk.y, vk.z, vk.w};
        const int m = d & 3;
        #pragma unroll
        for (int i = 0; i < 4; i++)
            #pragma unroll
            for (int j = 0; j < 4; j++)
                acc[i][j][m] = __fadd_rn(acc[i][j][m], __fmul_rn(qa[i], kb[j]));
    }
    size_t rb = ((size_t)(bi * 8 + h) * 512 + qt * 64);
    #pragma unroll
    for (int i = 0; i < 4; i++) {
        float4 o;
        o.x = __fmul_rn(__fadd_rn(__fadd_rn(acc[i][0][0], acc[i][0][1]), __fadd_rn(acc[i][0][2], acc[i][0][3])), 0.125f);
        o.y = __fmul_rn(__fadd_rn(__fadd_rn(acc[i][1][0], acc[i][1][1]), __fadd_rn(acc[i][1][2], acc[i][1][3])), 0.125f);
        o.z = __fmul_rn(__fadd_rn(__fadd_rn(acc[i][2][0], acc[i][2][1]), __fadd_rn(acc[i][2][2], acc[i][2][3])), 0.125f);
        o.w = __fmul_rn(__fadd_rn(__fadd_rn(acc[i][3][0], acc[i][3][1]), __fadd_rn(acc[i][3][2], acc[i][3][3])), 0.125f);
        *(float4*)&attnP[(rb + tm * 4 + i) * 512 + kt * 64 + tn * 4] = o;
    }
}

// ---------------- softmax (unchanged) ----------------
__global__ __launch_bounds__(256) void k_softmax(float* __restrict__ attnP) {
    __shared__ float ebuf[4][512];
    int wid = threadIdx.x >> 6, lane = threadIdx.x & 63;
    int row = blockIdx.x * 4 + wid;
    float* pr = attnP + (size_t)row * 512;
    float s[8], m = -INFINITY;
    for (int i = 0; i < 8; i++) { s[i] = pr[i * 64 + lane]; m = fmaxf(m, s[i]); }
    for (int off = 32; off; off >>= 1) m = fmaxf(m, __shfl_xor(m, off, 64));
    for (int i = 0; i < 8; i++)
        ebuf[wid][i * 64 + lane] = np_expf(__fsub_rn(s[i], m));
    __syncthreads();
    float sum = pairwise512(ebuf[wid], lane);
    for (int i = 0; i < 8; i++) pr[i * 64 + lane] = __fdiv_rn(ebuf[wid][i * 64 + lane], sum);
}

// ---------------- PV v2 (unchanged) ----------------
__global__ __launch_bounds__(256) void k_pv(const float* __restrict__ attnP,
                                            const float* __restrict__ qkv,
                                            float* __restrict__ ctx, int b0) {
    __shared__ float at_s[64][64];   // [k][q]
    __shared__ float v_s[64][64];    // [k][dh]
    int t = threadIdx.x;
    int bx = blockIdx.x;
    int qt = bx & 7, h = (bx >> 3) & 7, bi = bx >> 6;
    int b = b0 + bi;
    int tm = t & 15, tn = t >> 4;
    int lr = t >> 2, lf = (t & 3) * 16;
    float acc[4][4] = {};
    for (int c = 0; c < 8; c++) {
        const float* ar = attnP + ((size_t)(bi * 8 + h) * 512 + qt * 64 + lr) * 512 + c * 64 + lf;
        #pragma unroll
        for (int m = 0; m < 4; m++) {
            float4 a4 = *(const float4*)(ar + 4 * m);
            at_s[lf + 4 * m + 0][lr] = a4.x;
            at_s[lf + 4 * m + 1][lr] = a4.y;
            at_s[lf + 4 * m + 2][lr] = a4.z;
            at_s[lf + 4 * m + 3][lr] = a4.w;
        }
        const float* vr = qkv + (size_t)(b * 512 + c * 64 + lr) * 1536 + 1024 + h * 64 + lf;
        #pragma unroll
        for (int m = 0; m < 4; m++)
            *(float4*)&v_s[lr][lf + 4 * m] = *(const float4*)(vr + 4 * m);
        __syncthreads();
        #pragma unroll
        for (int kk = 0; kk < 64; kk++) {
            float4 a4 = *(const float4*)&at_s[kk][tm * 4];
            float4 v4 = *(const float4*)&v_s[kk][tn * 4];
            float av[4] = {a4.x, a4.y, a4.z, a4.w};
            float bv[4] = {v4.x, v4.y, v4.z, v4.w};
            #pragma unroll
            for (int i = 0; i < 4; i++)
                #pragma unroll
                for (int j = 0; j < 4; j++)
                    acc[i][j] = __fadd_rn(acc[i][j], __fmul_rn(av[i], bv[j]));
        }
        __syncthreads();
    }
    #pragma unroll
    for (int i = 0; i < 4; i++) {
        int q = qt * 64 + tm * 4 + i;
        *(float4*)&ctx[(size_t)(b * 512 + q) * 512 + h * 64 + tn * 4] =
            make_float4(acc[i][0], acc[i][1], acc[i][2], acc[i][3]);
    }
}

// ---------------- residual + LayerNorm (unchanged) ----------------
__global__ __launch_bounds__(256) void k_addln32(const float* __restrict__ xin,
                                                 const float* __restrict__ yin,
                                                 const float* __restrict__ ob,
                                                 const float* __restrict__ sc,
                                                 const float* __restrict__ bi,
                                                 float* __restrict__ xout) {
    __shared__ float buf[512];
    __shared__ float d2[512];
    __shared__ float stats[2];
    int row = blockIdx.x, t = threadIdx.x;
    const float* xr = xin + (size_t)row * 512;
    const float* yr = yin + (size_t)row * 512;
    float v0 = __fadd_rn(xr[t], yr[t]);
    float v1 = __fadd_rn(xr[t + 256], yr[t + 256]);
    if (ob) { v0 = __fadd_rn(v0, ob[t]); v1 = __fadd_rn(v1, ob[t + 256]); }
    buf[t] = v0; buf[t + 256] = v1;
    __syncthreads();
    int lane = t & 63;
    if (t < 64) {
        float s = pairwise512(buf, lane);
        if (lane == 0) stats[0] = __fdiv_rn(s, 512.0f);
    }
    __syncthreads();
    float mean = stats[0];
    float d0 = __fsub_rn(v0, mean), d1 = __fsub_rn(v1, mean);
    d2[t] = __fmul_rn(d0, d0); d2[t + 256] = __fmul_rn(d1, d1);
    __syncthreads();
    if (t < 64) {
        float s = pairwise512(d2, lane);
        if (lane == 0) {
            float var = __fdiv_rn(s, 512.0f);
            stats[1] = __fdiv_rn(1.0f, __fsqrt_rn(__fadd_rn(var, 1e-5f)));
        }
    }
    __syncthreads();
    float inv = stats[1];
    xout[(size_t)row * 512 + t]       = __fadd_rn(__fmul_rn(__fmul_rn(d0, inv), sc[t]), bi[t]);
    xout[(size_t)row * 512 + t + 256] = __fadd_rn(__fmul_rn(__fmul_rn(d1, inv), sc[t + 256]), bi[t + 256]);
}

// ---------------- norm denominator: PARALLEL f64 sum-of-squares -------------
// The kept-set is provably den-independent (|g| ordering == |x| ordering under
// monotone fl(x/den)*2048; thr=a+0.25(b-a) always lands in [a,b)), and den
// perturbations shift outputs by <=1 ulp relative (invisible at bf16 compare).
// Empirically: R2-R4 swapped den algorithms with bit-identical results, and
// R9-R14 pass with a den that differs from numpy's threaded-BLAS den anyway.
// So the serial-chain sdot (~400us/call) is replaced by a ~10us reduction.
__global__ __launch_bounds__(256) void k_sumsq(const float* __restrict__ x,
                                               double* __restrict__ part) {
    __shared__ double lds[4];
    size_t i0 = (size_t)blockIdx.x * 256 + threadIdx.x;
    double s = 0.0;
    for (size_t i = i0; i < (size_t)NTOT; i += 262144) {
        double v = (double)x[i];
        s = fma(v, v, s);
    }
    for (int off = 32; off; off >>= 1) s += __shfl_xor(s, off, 64);
    int wid = threadIdx.x >> 6, ln = threadIdx.x & 63;
    if (ln == 0) lds[wid] = s;
    __syncthreads();
    if (threadIdx.x == 0) part[blockIdx.x] = lds[0] + lds[1] + lds[2] + lds[3];
}

__global__ void k_fin(const double* __restrict__ part, float* __restrict__ den) {
    __shared__ double lds[4];
    int t = threadIdx.x;
    double s = 0.0;
    for (int i = t; i < 1024; i += 256) s += part[i];
    for (int off = 32; off; off >>= 1) s += __shfl_xor(s, off, 64);
    int wid = t >> 6, ln = t & 63;
    if (ln == 0) lds[wid] = s;
    __syncthreads();
    if (t == 0) {
        double tot = lds[0] + lds[1] + lds[2] + lds[3];
        den[0] = __fadd_rn((float)sqrt(tot), 1e-8f);
    }
}

// ---------------- quantile machinery (unchanged) ----------------
__global__ void k_qinit(unsigned long long* state, unsigned int* hist) {
    int t = threadIdx.x;
    hist[t] = 0;
    if (t == 0) { state[0] = 0; state[1] = R0Q; state[2] = 0; state[3] = ~0ULL; }
}

__global__ __launch_bounds__(256) void k_gkeys32(const float* __restrict__ x,
                                                 const float* __restrict__ den_p,
                                                 unsigned int* __restrict__ keys) {
    int i = blockIdx.x * 256 + threadIdx.x;
    float g = __fmul_rn(__fdiv_rn(x[i], den_p[0]), 2048.0f);
    keys[i] = __float_as_uint(fabsf(g));
}

__global__ __launch_bounds__(256) void k_hist32(const unsigned int* __restrict__ keys,
                                                const unsigned long long* __restrict__ state,
                                                unsigned int* __restrict__ hist, int shift) {
    __shared__ unsigned int h[256];
    h[threadIdx.x] = 0;
    __syncthreads();
    unsigned int pref = (unsigned int)state[0];
    for (size_t i = (size_t)blockIdx.x * 256 + threadIdx.x; i < (size_t)NTOT; i += 262144) {
        unsigned int k = keys[i];
        if (shift == 24 || (k >> (shift + 8)) == pref)
            atomicAdd(&h[(k >> shift) & 255u], 1u);
    }
    __syncthreads();
    atomicAdd(&hist[threadIdx.x], h[threadIdx.x]);
}

__global__ void k_scan32(unsigned long long* state, unsigned int* hist) {
    if (threadIdx.x == 0) {
        unsigned long long r = state[1], cum = 0;
        int b = 0;
        for (; b < 256; b++) {
            unsigned long long c = hist[b];
            if (cum + c > r) break;
            cum += c;
        }
        state[0] = (state[0] << 8) | (unsigned long long)b;
        state[1] = r - cum;
    }
    __syncthreads();
    hist[threadIdx.x] = 0;
}

__global__ __launch_bounds__(256) void k_fixcnt32(const unsigned int* __restrict__ keys,
                                                  unsigned long long* __restrict__ state) {
    __shared__ unsigned long long lc[4];
    __shared__ unsigned int lm[4];
    unsigned int v0 = (unsigned int)state[0];
    unsigned long long cnt = 0;
    unsigned int mn = 0xFFFFFFFFu;
    for (size_t i = (size_t)blockIdx.x * 256 + threadIdx.x; i < (size_t)NTOT; i += 262144) {
        unsigned int k = keys[i];
        if (k <= v0) cnt++;
        else if (k < mn) mn = k;
    }
    for (int off = 32; off; off >>= 1) {
        cnt += __shfl_xor(cnt, off, 64);
        unsigned int o = __shfl_xor(mn, off, 64);
        if (o < mn) mn = o;
    }
    int wid = threadIdx.x >> 6, ln = threadIdx.x & 63;
    if (ln == 0) { lc[wid] = cnt; lm[wid] = mn; }
    __syncthreads();
    if (threadIdx.x == 0) {
        unsigned long long c = lc[0] + lc[1] + lc[2] + lc[3];
        unsigned int m2 = lm[0];
        if (lm[1] < m2) m2 = lm[1];
        if (lm[2] < m2) m2 = lm[2];
        if (lm[3] < m2) m2 = lm[3];
        atomicAdd(&state[2], c);
        atomicMin(&state[3], (unsigned long long)m2);
    }
}

__global__ void k_thr32(const unsigned long long* __restrict__ state,
                        float* __restrict__ thr_p) {
    if (threadIdx.x == 0 && blockIdx.x == 0) {
        float a = __uint_as_float((unsigned int)state[0]);
        float b = (state[2] > R0Q + 1) ? a : __uint_as_float((unsigned int)state[3]);
        thr_p[0] = __fadd_rn(a, __fmul_rn(__fsub_rn(b, a), 0.25f));
    }
}

__global__ __launch_bounds__(256) void k_damp32(float* __restrict__ x,
                                                const float* __restrict__ den_p,
                                                const float* __restrict__ thr_p,
                                                float c1, float c2) {
    int i = blockIdx.x * 256 + threadIdx.x;
    float g = __fmul_rn(__fdiv_rn(x[i], den_p[0]), 2048.0f);
    float v = (fabsf(g) > thr_p[0]) ? g : 0.0f;
    x[i] = __fmul_rn(__fmul_rn(v, c1), c2);
}

// ---------------- host orchestration ----------------------------------------
extern "C" void kernel_launch(void* const* d_in, const int* in_sizes, int n_in,
                              void* d_out, int out_size, void* d_ws, size_t ws_size,
                              hipStream_t stream) {
    const int*   src     = (const int*)d_in[0];
    const float* emb     = (const float*)d_in[1];
    const float* pos     = (const float*)d_in[2];
    const float* qkv_w   = (const float*)d_in[3];
    const float* qkv_b   = (const float*)d_in[4];
    const float* attn_ow = (const float*)d_in[5];
    const float* attn_ob = (const float*)d_in[6];
    const float* ln1_s   = (const float*)d_in[7];
    const float* ln1_b   = (const float*)d_in[8];
    const float* ln2_s   = (const float*)d_in[9];
    const float* ln2_b   = (const float*)d_in[10];
    const float* ff1_w   = (const float*)d_in[11];
    const float* ff1_b   = (const float*)d_in[12];
    const float* ff2_w   = (const float*)d_in[13];
    const float* ff2_b   = (const float*)d_in[14];
    const float* head_w  = (const float*)d_in[15];
    const float* head_b  = (const float*)d_in[16];

    char* ws = (char*)d_ws;
    float* x    = (float*)(ws + 0);
    float* qkv  = (float*)(ws + 16777216ULL);           // 50.3 MB
    float* attnP= (float*)(ws + 67108864ULL);           // 67.1 MB (8 batches) — aliases ffh
    float* ffh  = (float*)(ws + 67108864ULL);           // ff hidden (after attention)
    float* y    = (float*)(ws + 134217728ULL);
    float* ctx  = (float*)(ws + 150994944ULL);
    unsigned int* keys = (unsigned int*)ctx;            // aliases ctx (dead by then)
    double* part = (double*)(ws + 184549376ULL);        // 1024 f64 partials
    float*  den  = (float*)(ws + 184557568ULL);
    float*  thr  = (float*)(ws + 184557572ULL);
    unsigned int* hist = (unsigned int*)(ws + 184561664ULL);
    unsigned long long* state = (unsigned long long*)(ws + 184565760ULL);

    float sc_emb = (float)sqrt(512.0);                 // np.sqrt(D).astype(f32)
    float c1 = (float)pow(0.99, 1.0 / 6.0);            // np.float32(DAMP**(1/L))

    k_embed32<<<16384, 256, 0, stream>>>(src, emb, pos, x, sc_emb);

    for (int l = 0; l < LL; l++) {
        // qkv = x @ qkv_w^T + qkv_b   [8192,1536]
        k_gemm6<<<dim3(8, 64), 256, 0, stream>>>(
            x, qkv_w + (size_t)l * 1536 * 512, qkv_b + (size_t)l * 1536, qkv, 1536, 512, 1);
        // attention: 2 phases of 8 batches
        for (int ph = 0; ph < 2; ph++) {
            int b0 = ph * 8;
            k_scores<<<4096, 256, 0, stream>>>(qkv, attnP, b0);
            k_softmax<<<8192, 256, 0, stream>>>(attnP);
            k_pv<<<512, 256, 0, stream>>>(attnP, qkv, ctx, b0);
        }
        // proj (raw matmul; ob added in addln to match ((x + mm) + ob) order)
        k_gemm6<<<dim3(3, 64), 256, 0, stream>>>(
            ctx, attn_ow + (size_t)l * 512 * 512, nullptr, y, 512, 512, 0);
        k_addln32<<<8192, 256, 0, stream>>>(x, y, attn_ob + (size_t)l * 512,
                                            ln1_s + (size_t)l * 512, ln1_b + (size_t)l * 512, x);
        // FF
        k_gemm6<<<dim3(11, 64), 256, 0, stream>>>(
            x, ff1_w + (size_t)l * 2048 * 512, ff1_b + (size_t)l * 2048, ffh, 2048, 512, 3);
        k_gemm6<<<dim3(3, 64), 256, 0, stream>>>(
            ffh, ff2_w + (size_t)l * 512 * 2048, ff2_b + (size_t)l * 512, y, 512, 2048, 1);
        k_addln32<<<8192, 256, 0, stream>>>(x, y, nullptr,
                                            ln2_s + (size_t)l * 512, ln2_b + (size_t)l * 512, x);
        // resonance: parallel den (set-invariant), radix-select quantile, damp
        k_sumsq<<<1024, 256, 0, stream>>>(x, part);
        k_fin<<<1, 256, 0, stream>>>(part, den);
        k_qinit<<<1, 256, 0, stream>>>(state, hist);
        k_gkeys32<<<16384, 256, 0, stream>>>(x, den, keys);
        for (int p = 0; p < 4; p++) {
            k_hist32<<<1024, 256, 0, stream>>>(keys, state, hist, 24 - 8 * p);
            k_scan32<<<1, 256, 0, stream>>>(state, hist);
        }
        k_fixcnt32<<<1024, 256, 0, stream>>>(keys, state);
        k_thr32<<<1, 1, 0, stream>>>(state, thr);
        float c2 = (float)pow(0.99, (double)l / 6.0);  // np.float32(DAMP**(i/L))
        k_damp32<<<16384, 256, 0, stream>>>(x, den, thr, c1, c2);
    }

    // head: out = x @ head_w^T + head_b   [8192,10000]
    k_gemm6<<<dim3(53, 64), 256, 0, stream>>>(
        x, head_w, head_b, (float*)d_out, 10000, 512, 1);
}